// Round 2
// baseline (1257.875 us; speedup 1.0000x reference)
//
#include <hip/hip_runtime.h>
#include <hip/hip_bf16.h>

typedef unsigned short u16;
typedef __bf16 bf16x8 __attribute__((ext_vector_type(8)));
typedef float f32x4 __attribute__((ext_vector_type(4)));

static __device__ __forceinline__ float b2f(u16 x) {
    unsigned int u = ((unsigned int)x) << 16;
    float f; __builtin_memcpy(&f, &u, 4); return f;
}
static __device__ __forceinline__ u16 f2b(float f) {
    unsigned int u; __builtin_memcpy(&u, &f, 4);
    unsigned int lsb = (u >> 16) & 1u;
    u += 0x7fffu + lsb;
    return (u16)(u >> 16);
}

// ---------------- transpose+convert: src fp32 [R][C] -> dst bf16 [C][R] ----------------
__global__ __launch_bounds__(256) void transpose_f2b(const float* __restrict__ src,
                                                     u16* __restrict__ dst,
                                                     int R, int C) {
    __shared__ u16 tile[32][33];
    int c0 = blockIdx.x * 32, r0 = blockIdx.y * 32;
    int tx = threadIdx.x & 31, ty = threadIdx.x >> 5;  // ty 0..7
    for (int i = ty; i < 32; i += 8) {
        int r = r0 + i, c = c0 + tx;
        tile[i][tx] = (r < R && c < C) ? f2b(src[(long)r * C + c]) : (u16)0;
    }
    __syncthreads();
    for (int i = ty; i < 32; i += 8) {
        int c = c0 + i, r = r0 + tx;
        if (c < C && r < R) dst[(long)c * R + r] = tile[tx][i];
    }
}

// ---------------- concat 3 fp32 bias vectors of 1024 ----------------
__global__ __launch_bounds__(256) void concat3(const float* a, const float* b, const float* c,
                                               float* out) {
    int i = blockIdx.x * 256 + threadIdx.x;
    if (i < 1024) out[i] = a[i];
    else if (i < 2048) out[i] = b[i - 1024];
    else if (i < 3072) out[i] = c[i - 2048];
}

// ---------------- generic batched bt-GEMM ----------------
// C[z][M][N] = alpha * A[z][M][K] * B[z][N][K]^T + bias[N], optional relu.
// A is bf16 unless a_fp32 (converted during staging). B is bf16. C bf16 unless c_fp32.
// All lda/ldb/ldc/strides are in ELEMENTS of the respective dtype.
#define BM 128
#define BN 128
#define BK 32
__global__ __launch_bounds__(256) void gemm_bt(
    const void* __restrict__ A, const u16* __restrict__ B,
    const float* __restrict__ bias, void* __restrict__ C,
    int M, int N, int K, int lda, int ldb, int ldc,
    int zdiv, long sA1, long sA2, long sB1, long sB2, long sC1, long sC2,
    float alpha, int relu, int a_fp32, int c_fp32) {
    __shared__ __align__(16) u16 As[BM][BK];
    __shared__ __align__(16) u16 Bs[BN][BK];

    int z = blockIdx.z;
    long offA = (long)(z / zdiv) * sA1 + (long)(z % zdiv) * sA2;
    const u16* Bb = B + (long)(z / zdiv) * sB1 + (long)(z % zdiv) * sB2;
    long offC = (long)(z / zdiv) * sC1 + (long)(z % zdiv) * sC2;

    int m0 = blockIdx.y * BM;
    int n0 = blockIdx.x * BN;

    int tid = threadIdx.x;
    int lane = tid & 63;
    int wave = tid >> 6;
    int wm = (wave >> 1) * 64;
    int wn = (wave & 1) * 64;
    int lrow = lane & 15;
    int quad = lane >> 4;

    f32x4 acc[4][4];
#pragma unroll
    for (int i = 0; i < 4; i++)
#pragma unroll
        for (int j = 0; j < 4; j++) acc[i][j] = (f32x4){0.f, 0.f, 0.f, 0.f};

    for (int k0 = 0; k0 < K; k0 += BK) {
#pragma unroll
        for (int i = 0; i < 2; i++) {
            int idx = tid * 2 + i;
            int row = idx >> 2;
            int segc = (idx & 3) * 8;
            int ar = m0 + row;
            if (a_fp32) {
                const float* Af = (const float*)A + offA;
                union { uint4 u; u16 h[8]; } pk;
                if (ar < M) {
                    float4 f0 = *(const float4*)(Af + (long)ar * lda + k0 + segc);
                    float4 f1 = *(const float4*)(Af + (long)ar * lda + k0 + segc + 4);
                    pk.h[0] = f2b(f0.x); pk.h[1] = f2b(f0.y);
                    pk.h[2] = f2b(f0.z); pk.h[3] = f2b(f0.w);
                    pk.h[4] = f2b(f1.x); pk.h[5] = f2b(f1.y);
                    pk.h[6] = f2b(f1.z); pk.h[7] = f2b(f1.w);
                } else {
                    pk.u = make_uint4(0, 0, 0, 0);
                }
                *(uint4*)&As[row][segc] = pk.u;
            } else {
                const u16* Ah = (const u16*)A + offA;
                uint4 va = make_uint4(0, 0, 0, 0);
                if (ar < M) va = *(const uint4*)(Ah + (long)ar * lda + k0 + segc);
                *(uint4*)&As[row][segc] = va;
            }
            uint4 vb = make_uint4(0, 0, 0, 0);
            int br = n0 + row;
            if (br < N) vb = *(const uint4*)(Bb + (long)br * ldb + k0 + segc);
            *(uint4*)&Bs[row][segc] = vb;
        }
        __syncthreads();

        bf16x8 af[4], bfr[4];
#pragma unroll
        for (int mi = 0; mi < 4; mi++)
            af[mi] = *(const bf16x8*)&As[wm + mi * 16 + lrow][quad * 8];
#pragma unroll
        for (int ni = 0; ni < 4; ni++)
            bfr[ni] = *(const bf16x8*)&Bs[wn + ni * 16 + lrow][quad * 8];
#pragma unroll
        for (int mi = 0; mi < 4; mi++)
#pragma unroll
            for (int ni = 0; ni < 4; ni++)
                acc[mi][ni] = __builtin_amdgcn_mfma_f32_16x16x32_bf16(
                    af[mi], bfr[ni], acc[mi][ni], 0, 0, 0);
        __syncthreads();
    }

#pragma unroll
    for (int mi = 0; mi < 4; mi++) {
        int r0w = m0 + wm + mi * 16 + quad * 4;
#pragma unroll
        for (int ni = 0; ni < 4; ni++) {
            int col = n0 + wn + ni * 16 + lrow;
            if (col >= N) continue;
            float bv = bias ? bias[col] : 0.f;
#pragma unroll
            for (int r = 0; r < 4; r++) {
                int rr = r0w + r;
                if (rr >= M) continue;
                float v = alpha * acc[mi][ni][r] + bv;
                if (relu) v = fmaxf(v, 0.f);
                if (c_fp32)
                    ((float*)C)[offC + (long)rr * ldc + col] = v;
                else
                    ((u16*)C)[offC + (long)rr * ldc + col] = f2b(v);
            }
        }
    }
}

// ---------------- extract v from qkv (bf16), transposed per head ----------------
// qkv[(b*512+s)*3072 + 2048 + h*64 + d] -> vT[(b*16+h)*64*512 + d*512 + s]
__global__ __launch_bounds__(256) void split_v(const u16* __restrict__ qkv,
                                               u16* __restrict__ vT) {
    __shared__ u16 tile[32][33];
    int bh = blockIdx.z;
    int b = bh >> 4, h = bh & 15;
    int s0 = blockIdx.x * 32;
    int d0 = blockIdx.y * 32;
    int tx = threadIdx.x & 31, ty = threadIdx.x >> 5;
    for (int i = ty; i < 32; i += 8)
        tile[i][tx] = qkv[((long)(b * 512 + s0 + i)) * 3072 + 2048 + h * 64 + d0 + tx];
    __syncthreads();
    for (int i = ty; i < 32; i += 8)
        vT[((long)bh * 64 + d0 + i) * 512 + s0 + tx] = tile[tx][i];
}

// ---------------- masked softmax over fp32 rows of attn (in place) ----------------
__global__ __launch_bounds__(256) void softmax_rows_f32(float* __restrict__ attn,
                                                        const int* __restrict__ mask) {
    int wave = threadIdx.x >> 6;
    int lane = threadIdx.x & 63;
    long row = (long)blockIdx.x * 4 + wave;  // over B*H*S rows
    int b = (int)(row >> 13);                // / (16*512)
    float* p = attn + row * 512;
    const int* mrow = mask + b * 512;
    float v[8];
    float mx = -3.0e38f;
#pragma unroll
    for (int j = 0; j < 8; j++) {
        int c = lane + j * 64;
        float s = p[c];
        if (mrow[c] == 0) s = -1e9f;
        v[j] = s;
        mx = fmaxf(mx, s);
    }
#pragma unroll
    for (int off = 32; off >= 1; off >>= 1) mx = fmaxf(mx, __shfl_xor(mx, off));
    float sum = 0.f;
#pragma unroll
    for (int j = 0; j < 8; j++) {
        v[j] = expf(v[j] - mx);
        sum += v[j];
    }
#pragma unroll
    for (int off = 32; off >= 1; off >>= 1) sum += __shfl_xor(sum, off);
    float inv = 1.0f / sum;
#pragma unroll
    for (int j = 0; j < 8; j++) p[lane + j * 64] = v[j] * inv;
}

// ---------------- out = LayerNorm(a + r) * g + beta, D=1024, one block per row ----
// a bf16; r fp32 if r_fp32 else bf16; out fp32 if out_fp32 else bf16.
__global__ __launch_bounds__(256) void add_ln(const u16* __restrict__ a,
                                              const void* __restrict__ r, int r_fp32,
                                              const float* __restrict__ g,
                                              const float* __restrict__ beta,
                                              void* __restrict__ out, int out_fp32) {
    long row = blockIdx.x;
    const u16* pa = a + row * 1024;
    int tid = threadIdx.x;
    float v[4];
    float sum = 0.f, sq = 0.f;
#pragma unroll
    for (int j = 0; j < 4; j++) {
        int c = tid + j * 256;
        float rv = r_fp32 ? ((const float*)r)[row * 1024 + c]
                          : b2f(((const u16*)r)[row * 1024 + c]);
        float x = b2f(pa[c]) + rv;
        v[j] = x;
        sum += x;
        sq += x * x;
    }
#pragma unroll
    for (int off = 32; off >= 1; off >>= 1) {
        sum += __shfl_xor(sum, off);
        sq += __shfl_xor(sq, off);
    }
    __shared__ float red[2][4];
    int wave = tid >> 6, lane = tid & 63;
    if (lane == 0) { red[0][wave] = sum; red[1][wave] = sq; }
    __syncthreads();
    sum = red[0][0] + red[0][1] + red[0][2] + red[0][3];
    sq = red[1][0] + red[1][1] + red[1][2] + red[1][3];
    float mu = sum * (1.f / 1024.f);
    float var = sq * (1.f / 1024.f) - mu * mu;
    float rstd = rsqrtf(var + 1e-6f);
#pragma unroll
    for (int j = 0; j < 4; j++) {
        int c = tid + j * 256;
        float y = (v[j] - mu) * rstd * g[c] + beta[c];
        if (out_fp32) ((float*)out)[row * 1024 + c] = y;
        else ((u16*)out)[row * 1024 + c] = f2b(y);
    }
}

extern "C" void kernel_launch(void* const* d_in, const int* in_sizes, int n_in,
                              void* d_out, int out_size, void* d_ws, size_t ws_size,
                              hipStream_t stream) {
    const float* x   = (const float*)d_in[0];
    const float* Wq  = (const float*)d_in[1];
    const float* bq  = (const float*)d_in[2];
    const float* Wk  = (const float*)d_in[3];
    const float* bk  = (const float*)d_in[4];
    const float* Wv  = (const float*)d_in[5];
    const float* bv  = (const float*)d_in[6];
    const float* Wo  = (const float*)d_in[7];
    const float* bo  = (const float*)d_in[8];
    const float* g1  = (const float*)d_in[9];
    const float* be1 = (const float*)d_in[10];
    const float* w1  = (const float*)d_in[11];
    const float* b1  = (const float*)d_in[12];
    const float* w2  = (const float*)d_in[13];
    const float* b2  = (const float*)d_in[14];
    const float* g2  = (const float*)d_in[15];
    const float* be2 = (const float*)d_in[16];
    const int* mask  = (const int*)d_in[17];

    float* out = (float*)d_out;                   // [8192][1024] fp32
    float* attn = out + (long)8192 * 1024;        // [256][512][512] fp32 (scores -> probs)

    char* w = (char*)d_ws;
    auto alloc = [&](size_t bytes) {
        char* p = w;
        w += (bytes + 255) & ~(size_t)255;
        return p;
    };
    u16* WqkvT = (u16*)alloc(3072L * 1024 * 2);
    u16* WoT   = (u16*)alloc(1024L * 1024 * 2);
    u16* w1T   = (u16*)alloc(4096L * 1024 * 2);
    u16* w2T   = (u16*)alloc(1024L * 4096 * 2);
    float* bqkv = (float*)alloc(3072L * 4);
    char* P1 = alloc(8192L * 4096 * 2);  // qkv (48MB) -> y (16MB) -> ff (64MB)
    u16* qkv = (u16*)P1;
    u16* y   = (u16*)P1;
    u16* ff  = (u16*)P1;
    char* P2 = alloc(256L * 64 * 512 * 2);  // vT -> y2
    u16* vT = (u16*)P2;
    u16* y2 = (u16*)P2;
    u16* ctx = (u16*)alloc(8192L * 1024 * 2);
    u16* x1  = (u16*)alloc(8192L * 1024 * 2);

    dim3 blk(256);

    // weight transposes + fp32->bf16 (B^T form for all GEMMs)
    transpose_f2b<<<dim3(32, 32), blk, 0, stream>>>(Wq, WqkvT, 1024, 1024);
    transpose_f2b<<<dim3(32, 32), blk, 0, stream>>>(Wk, WqkvT + 1024L * 1024, 1024, 1024);
    transpose_f2b<<<dim3(32, 32), blk, 0, stream>>>(Wv, WqkvT + 2048L * 1024, 1024, 1024);
    transpose_f2b<<<dim3(32, 32), blk, 0, stream>>>(Wo, WoT, 1024, 1024);
    transpose_f2b<<<dim3(128, 32), blk, 0, stream>>>(w1, w1T, 1024, 4096);
    transpose_f2b<<<dim3(32, 128), blk, 0, stream>>>(w2, w2T, 4096, 1024);
    concat3<<<12, blk, 0, stream>>>(bq, bk, bv, bqkv);

    // qkv = x @ [Wq|Wk|Wv] + [bq|bk|bv]   (M=8192, N=3072, K=1024), A fp32 -> bf16 out
    gemm_bt<<<dim3(24, 64, 1), blk, 0, stream>>>(
        x, WqkvT, bqkv, qkv, 8192, 3072, 1024, 1024, 1024, 3072,
        1, 0, 0, 0, 0, 0, 0, 1.0f, 0, 1, 0);

    // vT per head (bf16)
    split_v<<<dim3(16, 2, 256), blk, 0, stream>>>(qkv, vT);

    // scores = (q @ k^T)/8 -> fp32 into attn region, batch = B*H = 256
    gemm_bt<<<dim3(4, 4, 256), blk, 0, stream>>>(
        qkv + 0, qkv + 1024, nullptr, attn, 512, 512, 64, 3072, 3072, 512,
        16, (long)512 * 3072, 64, (long)512 * 3072, 64,
        (long)16 * 512 * 512, (long)512 * 512, 0.125f, 0, 0, 1);

    softmax_rows_f32<<<32768, blk, 0, stream>>>(attn, mask);

    // ctx = attn @ v, written directly in merged-head layout (M=512, N=64, K=512)
    gemm_bt<<<dim3(1, 4, 256), blk, 0, stream>>>(
        attn, vT, nullptr, ctx, 512, 64, 512, 512, 512, 1024,
        16, (long)16 * 512 * 512, (long)512 * 512,
        (long)16 * 64 * 512, (long)64 * 512,
        (long)512 * 1024, 64, 1.0f, 0, 1, 0);

    // y = ctx @ Wo + bo
    gemm_bt<<<dim3(8, 64, 1), blk, 0, stream>>>(
        ctx, WoT, bo, y, 8192, 1024, 1024, 1024, 1024, 1024,
        1, 0, 0, 0, 0, 0, 0, 1.0f, 0, 0, 0);

    // x1 = LN(y + x)   (r fp32, out bf16)
    add_ln<<<8192, blk, 0, stream>>>(y, x, 1, g1, be1, x1, 0);

    // ff = relu(x1 @ w1 + b1)
    gemm_bt<<<dim3(32, 64, 1), blk, 0, stream>>>(
        x1, w1T, b1, ff, 8192, 4096, 1024, 1024, 1024, 4096,
        1, 0, 0, 0, 0, 0, 0, 1.0f, 1, 0, 0);

    // y2 = ff @ w2 + b2
    gemm_bt<<<dim3(8, 64, 1), blk, 0, stream>>>(
        ff, w2T, b2, y2, 8192, 1024, 4096, 4096, 4096, 1024,
        1, 0, 0, 0, 0, 0, 0, 1.0f, 0, 0, 0);

    // out = LN(y2 + x1)   (r bf16, out fp32)
    add_ln<<<8192, blk, 0, stream>>>(y2, x1, 0, g2, be2, out, 1);
}

// Round 3
// 932.880 us; speedup vs baseline: 1.3484x; 1.3484x over previous
//
#include <hip/hip_runtime.h>
#include <hip/hip_bf16.h>

typedef unsigned short u16;
typedef __bf16 bf16x8 __attribute__((ext_vector_type(8)));
typedef float f32x4 __attribute__((ext_vector_type(4)));

static __device__ __forceinline__ float b2f(u16 x) {
    unsigned int u = ((unsigned int)x) << 16;
    float f; __builtin_memcpy(&f, &u, 4); return f;
}
static __device__ __forceinline__ u16 f2b(float f) {
    unsigned int u; __builtin_memcpy(&u, &f, 4);
    unsigned int lsb = (u >> 16) & 1u;
    u += 0x7fffu + lsb;
    return (u16)(u >> 16);
}

// async 16B global->LDS (wave-uniform LDS base + lane*16)
static __device__ __forceinline__ void gload16(const u16* g, u16* l) {
    __builtin_amdgcn_global_load_lds(
        (const __attribute__((address_space(1))) unsigned int*)g,
        (__attribute__((address_space(3))) unsigned int*)l, 16, 0, 0);
}

// ---------------- transpose+convert: src fp32 [R][C] -> dst bf16 [C][R] ----------------
__global__ __launch_bounds__(256) void transpose_f2b(const float* __restrict__ src,
                                                     u16* __restrict__ dst,
                                                     int R, int C) {
    __shared__ u16 tile[32][33];
    int c0 = blockIdx.x * 32, r0 = blockIdx.y * 32;
    int tx = threadIdx.x & 31, ty = threadIdx.x >> 5;
    for (int i = ty; i < 32; i += 8) {
        int r = r0 + i, c = c0 + tx;
        tile[i][tx] = (r < R && c < C) ? f2b(src[(long)r * C + c]) : (u16)0;
    }
    __syncthreads();
    for (int i = ty; i < 32; i += 8) {
        int c = c0 + i, r = r0 + tx;
        if (c < C && r < R) dst[(long)c * R + r] = tile[tx][i];
    }
}

// ---------------- concat 3 fp32 bias vectors of 1024 ----------------
__global__ __launch_bounds__(256) void concat3(const float* a, const float* b, const float* c,
                                               float* out) {
    int i = blockIdx.x * 256 + threadIdx.x;
    if (i < 1024) out[i] = a[i];
    else if (i < 2048) out[i] = b[i - 1024];
    else if (i < 3072) out[i] = c[i - 2048];
}

// ---------------- fp32 -> bf16 bulk convert ----------------
__global__ __launch_bounds__(256) void conv_f2b(const float* __restrict__ src,
                                                u16* __restrict__ dst, long n) {
    long i = ((long)blockIdx.x * 256 + threadIdx.x) * 4;
    if (i >= n) return;
    float4 f = *(const float4*)(src + i);
    ushort4 o;
    o.x = f2b(f.x); o.y = f2b(f.y); o.z = f2b(f.z); o.w = f2b(f.w);
    *(ushort4*)(dst + i) = o;
}

// ---------------- m97-style bt-GEMM (all dims multiples of 128/BK) ----------------
// C[M][N] = A[M][K] * B[N][K]^T + bias[N], optional relu. A,B,C bf16, bias fp32.
#define BM 128
#define BN 128
#define BK 32
__global__ __launch_bounds__(256) void gemm_bt(
    const u16* __restrict__ A, const u16* __restrict__ B,
    const float* __restrict__ bias, u16* __restrict__ C,
    int M, int N, int K, int lda, int ldb, int ldc, int relu) {
    __shared__ __align__(16) u16 As[BM][BK];
    __shared__ __align__(16) u16 Bs[BN][BK];

    int m0 = blockIdx.y * BM;
    int n0 = blockIdx.x * BN;
    int tid = threadIdx.x;
    int lane = tid & 63;
    int wave = tid >> 6;
    int wm = (wave >> 1) * 64;
    int wn = (wave & 1) * 64;
    int lrow = lane & 15;
    int quad = lane >> 4;

    f32x4 acc[4][4];
#pragma unroll
    for (int i = 0; i < 4; i++)
#pragma unroll
        for (int j = 0; j < 4; j++) acc[i][j] = (f32x4){0.f, 0.f, 0.f, 0.f};

    const u16* Arow = A + (long)m0 * lda;
    const u16* Brow = B + (long)n0 * ldb;

    for (int k0 = 0; k0 < K; k0 += BK) {
#pragma unroll
        for (int i = 0; i < 2; i++) {
            int idx = (i * 4 + wave) * 64 + lane;
            int row = idx >> 2;
            int seg = (idx & 3) * 8;
            gload16(Arow + (long)row * lda + k0 + seg, &As[0][0] + (i * 4 + wave) * 512);
            gload16(Brow + (long)row * ldb + k0 + seg, &Bs[0][0] + (i * 4 + wave) * 512);
        }
        __syncthreads();

        bf16x8 af[4], bfr[4];
#pragma unroll
        for (int mi = 0; mi < 4; mi++)
            af[mi] = *(const bf16x8*)&As[wm + mi * 16 + lrow][quad * 8];
#pragma unroll
        for (int ni = 0; ni < 4; ni++)
            bfr[ni] = *(const bf16x8*)&Bs[wn + ni * 16 + lrow][quad * 8];
#pragma unroll
        for (int mi = 0; mi < 4; mi++)
#pragma unroll
            for (int ni = 0; ni < 4; ni++)
                acc[mi][ni] = __builtin_amdgcn_mfma_f32_16x16x32_bf16(
                    af[mi], bfr[ni], acc[mi][ni], 0, 0, 0);
        __syncthreads();
    }

#pragma unroll
    for (int mi = 0; mi < 4; mi++) {
        int r0w = m0 + wm + mi * 16 + quad * 4;
#pragma unroll
        for (int ni = 0; ni < 4; ni++) {
            int col = n0 + wn + ni * 16 + lrow;
            float bv = bias ? bias[col] : 0.f;
#pragma unroll
            for (int r = 0; r < 4; r++) {
                float v = acc[mi][ni][r] + bv;
                if (relu) v = fmaxf(v, 0.f);
                C[(long)(r0w + r) * ldc + col] = f2b(v);
            }
        }
    }
}

// ---------------- extract v from qkv (bf16), transposed per head ----------------
__global__ __launch_bounds__(256) void split_v(const u16* __restrict__ qkv,
                                               u16* __restrict__ vT) {
    __shared__ u16 tile[32][33];
    int bh = blockIdx.z;
    int b = bh >> 4, h = bh & 15;
    int s0 = blockIdx.x * 32;
    int d0 = blockIdx.y * 32;
    int tx = threadIdx.x & 31, ty = threadIdx.x >> 5;
    for (int i = ty; i < 32; i += 8)
        tile[i][tx] = qkv[((long)(b * 512 + s0 + i)) * 3072 + 2048 + h * 64 + d0 + tx];
    __syncthreads();
    for (int i = ty; i < 32; i += 8)
        vT[((long)bh * 64 + d0 + i) * 512 + s0 + tx] = tile[tx][i];
}

// ---------------- fused attention: scores + mask + softmax + PV ----------------
// grid (8, 256): x = 64-row Q tile, y = b*16+h. 256 threads = 4 waves.
// Writes probs fp32 to attnOut[bh][q][k] and ctx bf16 merged-head [b*512+q][h*64+d].
__global__ __launch_bounds__(256) void attn_fused(
    const u16* __restrict__ qkv, const u16* __restrict__ vT,
    const int* __restrict__ mask, float* __restrict__ attnOut,
    u16* __restrict__ ctx) {
    __shared__ __align__(16) u16 s_tile[128][72];     // Q then K-chunk staging
    __shared__ __align__(16) u16 s_p[4][16][136];     // per-wave P chunk (A-layout)
    __shared__ unsigned long long m_bits[8];

    int mtile = blockIdx.x;
    int bh = blockIdx.y;
    int b = bh >> 4, h = bh & 15;
    int tid = threadIdx.x, lane = tid & 63, wave = tid >> 6;
    int lrow = lane & 15, quad = lane >> 4;
    int m0 = mtile * 64;

    const u16* Qbase = qkv + (long)(b * 512) * 3072 + h * 64;
    const u16* Kbase = Qbase + 1024;

    {   // mask bitmask: bit j of m_bits[c] = (mask[b*512 + c*64 + j] != 0)
        int i0 = wave * 64 + lane;
        unsigned long long bl0 = __ballot(mask[b * 512 + i0] != 0);
        if (lane == 0) m_bits[wave] = bl0;
        unsigned long long bl1 = __ballot(mask[b * 512 + 256 + i0] != 0);
        if (lane == 0) m_bits[4 + wave] = bl1;
    }

    // stage Q tile [64][64]
#pragma unroll
    for (int i = 0; i < 2; i++) {
        int idx = i * 256 + tid;
        int r = idx >> 3, c = (idx & 7) * 8;
        *(uint4*)&s_tile[r][c] = *(const uint4*)(Qbase + (long)(m0 + r) * 3072 + c);
    }
    __syncthreads();
    bf16x8 qf[2];
    qf[0] = *(const bf16x8*)&s_tile[wave * 16 + lrow][0 + quad * 8];
    qf[1] = *(const bf16x8*)&s_tile[wave * 16 + lrow][32 + quad * 8];
    __syncthreads();

    f32x4 sacc[32];
#pragma unroll
    for (int t = 0; t < 32; t++) sacc[t] = (f32x4){0.f, 0.f, 0.f, 0.f};

    // S = Q K^T over 4 chunks of 128 key-rows
    for (int nc = 0; nc < 4; nc++) {
#pragma unroll
        for (int i = 0; i < 4; i++) {
            int idx = i * 256 + tid;
            int r = idx >> 3, c = (idx & 7) * 8;
            *(uint4*)&s_tile[r][c] = *(const uint4*)(Kbase + (long)(nc * 128 + r) * 3072 + c);
        }
        __syncthreads();
#pragma unroll
        for (int ni = 0; ni < 8; ni++) {
            bf16x8 b0 = *(const bf16x8*)&s_tile[ni * 16 + lrow][0 + quad * 8];
            bf16x8 b1 = *(const bf16x8*)&s_tile[ni * 16 + lrow][32 + quad * 8];
            int t = nc * 8 + ni;
            sacc[t] = __builtin_amdgcn_mfma_f32_16x16x32_bf16(qf[0], b0, sacc[t], 0, 0, 0);
            sacc[t] = __builtin_amdgcn_mfma_f32_16x16x32_bf16(qf[1], b1, sacc[t], 0, 0, 0);
        }
        __syncthreads();
    }

    // mask + scale; lane holds rows quad*4+r, cols t*16+lrow
    float mx[4] = {-3.0e38f, -3.0e38f, -3.0e38f, -3.0e38f};
#pragma unroll
    for (int t = 0; t < 32; t++) {
        int col = t * 16 + lrow;
        int on = (int)((m_bits[col >> 6] >> (col & 63)) & 1ull);
#pragma unroll
        for (int r = 0; r < 4; r++) {
            float s = on ? sacc[t][r] * 0.125f : -1e9f;
            sacc[t][r] = s;
            mx[r] = fmaxf(mx[r], s);
        }
    }
#pragma unroll
    for (int off = 1; off < 16; off <<= 1)
#pragma unroll
        for (int r = 0; r < 4; r++) mx[r] = fmaxf(mx[r], __shfl_xor(mx[r], off));
    float sm[4] = {0.f, 0.f, 0.f, 0.f};
#pragma unroll
    for (int t = 0; t < 32; t++)
#pragma unroll
        for (int r = 0; r < 4; r++) {
            float e = __expf(sacc[t][r] - mx[r]);
            sacc[t][r] = e;
            sm[r] += e;
        }
#pragma unroll
    for (int off = 1; off < 16; off <<= 1)
#pragma unroll
        for (int r = 0; r < 4; r++) sm[r] += __shfl_xor(sm[r], off);
#pragma unroll
    for (int r = 0; r < 4; r++) sm[r] = 1.0f / sm[r];
#pragma unroll
    for (int t = 0; t < 32; t++)
#pragma unroll
        for (int r = 0; r < 4; r++) sacc[t][r] *= sm[r];

    // write probs fp32
    float* arow = attnOut + (long)bh * 512 * 512 + (long)(m0 + wave * 16 + quad * 4) * 512 + lrow;
#pragma unroll
    for (int t = 0; t < 32; t++)
#pragma unroll
        for (int r = 0; r < 4; r++) arow[(long)r * 512 + t * 16] = sacc[t][r];

    // PV: ctx[m][d] = sum_k P[m][k] V^T[d][k]
    f32x4 cacc[4];
#pragma unroll
    for (int ni = 0; ni < 4; ni++) cacc[ni] = (f32x4){0.f, 0.f, 0.f, 0.f};
    const u16* vh = vT + (long)bh * 64 * 512;

    for (int nc = 0; nc < 4; nc++) {
#pragma unroll
        for (int t2 = 0; t2 < 8; t2++) {
            int t = nc * 8 + t2;
#pragma unroll
            for (int r = 0; r < 4; r++)
                s_p[wave][quad * 4 + r][t2 * 16 + lrow] = f2b(sacc[t][r]);
        }
        __syncthreads();
#pragma unroll
        for (int kk = 0; kk < 4; kk++) {
            bf16x8 pf = *(const bf16x8*)&s_p[wave][lrow][kk * 32 + quad * 8];
#pragma unroll
            for (int ni = 0; ni < 4; ni++) {
                bf16x8 vf = *(const bf16x8*)(vh + (long)(ni * 16 + lrow) * 512 + nc * 128 + kk * 32 + quad * 8);
                cacc[ni] = __builtin_amdgcn_mfma_f32_16x16x32_bf16(pf, vf, cacc[ni], 0, 0, 0);
            }
        }
    }

    u16* crow = ctx + (long)(b * 512 + m0 + wave * 16 + quad * 4) * 1024 + h * 64 + lrow;
#pragma unroll
    for (int ni = 0; ni < 4; ni++)
#pragma unroll
        for (int r = 0; r < 4; r++) crow[(long)r * 1024 + ni * 16] = f2b(cacc[ni][r]);
}

// ---------------- out = LayerNorm(a + r) * g + beta ----------------
__global__ __launch_bounds__(256) void add_ln(const u16* __restrict__ a,
                                              const void* __restrict__ r, int r_fp32,
                                              const float* __restrict__ g,
                                              const float* __restrict__ beta,
                                              void* __restrict__ out, int out_fp32) {
    long row = blockIdx.x;
    const u16* pa = a + row * 1024;
    int tid = threadIdx.x;
    float v[4];
    float sum = 0.f, sq = 0.f;
#pragma unroll
    for (int j = 0; j < 4; j++) {
        int c = tid + j * 256;
        float rv = r_fp32 ? ((const float*)r)[row * 1024 + c]
                          : b2f(((const u16*)r)[row * 1024 + c]);
        float x = b2f(pa[c]) + rv;
        v[j] = x;
        sum += x;
        sq += x * x;
    }
#pragma unroll
    for (int off = 32; off >= 1; off >>= 1) {
        sum += __shfl_xor(sum, off);
        sq += __shfl_xor(sq, off);
    }
    __shared__ float red[2][4];
    int wave = tid >> 6, lane = tid & 63;
    if (lane == 0) { red[0][wave] = sum; red[1][wave] = sq; }
    __syncthreads();
    sum = red[0][0] + red[0][1] + red[0][2] + red[0][3];
    sq = red[1][0] + red[1][1] + red[1][2] + red[1][3];
    float mu = sum * (1.f / 1024.f);
    float var = sq * (1.f / 1024.f) - mu * mu;
    float rstd = rsqrtf(var + 1e-6f);
#pragma unroll
    for (int j = 0; j < 4; j++) {
        int c = tid + j * 256;
        float y = (v[j] - mu) * rstd * g[c] + beta[c];
        if (out_fp32) ((float*)out)[row * 1024 + c] = y;
        else ((u16*)out)[row * 1024 + c] = f2b(y);
    }
}

extern "C" void kernel_launch(void* const* d_in, const int* in_sizes, int n_in,
                              void* d_out, int out_size, void* d_ws, size_t ws_size,
                              hipStream_t stream) {
    const float* x   = (const float*)d_in[0];
    const float* Wq  = (const float*)d_in[1];
    const float* bq  = (const float*)d_in[2];
    const float* Wk  = (const float*)d_in[3];
    const float* bk  = (const float*)d_in[4];
    const float* Wv  = (const float*)d_in[5];
    const float* bv  = (const float*)d_in[6];
    const float* Wo  = (const float*)d_in[7];
    const float* bo  = (const float*)d_in[8];
    const float* g1  = (const float*)d_in[9];
    const float* be1 = (const float*)d_in[10];
    const float* w1  = (const float*)d_in[11];
    const float* b1  = (const float*)d_in[12];
    const float* w2  = (const float*)d_in[13];
    const float* b2  = (const float*)d_in[14];
    const float* g2  = (const float*)d_in[15];
    const float* be2 = (const float*)d_in[16];
    const int* mask  = (const int*)d_in[17];

    float* out = (float*)d_out;                   // [8192][1024] fp32
    float* attn = out + (long)8192 * 1024;        // [256][512][512] fp32

    char* w = (char*)d_ws;
    auto alloc = [&](size_t bytes) {
        char* p = w;
        w += (bytes + 255) & ~(size_t)255;
        return p;
    };
    u16* WqkvT = (u16*)alloc(3072L * 1024 * 2);
    u16* WoT   = (u16*)alloc(1024L * 1024 * 2);
    u16* w1T   = (u16*)alloc(4096L * 1024 * 2);
    u16* w2T   = (u16*)alloc(1024L * 4096 * 2);
    float* bqkv = (float*)alloc(3072L * 4);
    u16* xb    = (u16*)alloc(8192L * 1024 * 2);
    char* P1 = alloc(8192L * 4096 * 2);  // qkv (48MB) -> ff (64MB)
    u16* qkv = (u16*)P1;
    u16* ff  = (u16*)P1;
    char* P2 = alloc(256L * 64 * 512 * 2);  // vT -> y2
    u16* vT = (u16*)P2;
    u16* y2 = (u16*)P2;
    u16* ctx = (u16*)alloc(8192L * 1024 * 2);
    u16* x1  = (u16*)alloc(8192L * 1024 * 2);
    u16* y   = (u16*)alloc(8192L * 1024 * 2);

    dim3 blk(256);

    transpose_f2b<<<dim3(32, 32), blk, 0, stream>>>(Wq, WqkvT, 1024, 1024);
    transpose_f2b<<<dim3(32, 32), blk, 0, stream>>>(Wk, WqkvT + 1024L * 1024, 1024, 1024);
    transpose_f2b<<<dim3(32, 32), blk, 0, stream>>>(Wv, WqkvT + 2048L * 1024, 1024, 1024);
    transpose_f2b<<<dim3(32, 32), blk, 0, stream>>>(Wo, WoT, 1024, 1024);
    transpose_f2b<<<dim3(128, 32), blk, 0, stream>>>(w1, w1T, 1024, 4096);
    transpose_f2b<<<dim3(32, 128), blk, 0, stream>>>(w2, w2T, 4096, 1024);
    concat3<<<12, blk, 0, stream>>>(bq, bk, bv, bqkv);
    conv_f2b<<<8192, blk, 0, stream>>>(x, xb, 8192L * 1024);

    // qkv = xb @ [Wq|Wk|Wv]^T + bqkv   (M=8192, N=3072, K=1024)
    gemm_bt<<<dim3(24, 64), blk, 0, stream>>>(
        xb, WqkvT, bqkv, qkv, 8192, 3072, 1024, 1024, 1024, 3072, 0);

    split_v<<<dim3(16, 2, 256), blk, 0, stream>>>(qkv, vT);

    // fused attention: probs -> attn (fp32), ctx (bf16 merged heads)
    attn_fused<<<dim3(8, 256), blk, 0, stream>>>(qkv, vT, mask, attn, ctx);

    // y = ctx @ Wo^T + bo
    gemm_bt<<<dim3(8, 64), blk, 0, stream>>>(
        ctx, WoT, bo, y, 8192, 1024, 1024, 1024, 1024, 1024, 0);

    // x1 = LN(y + x)
    add_ln<<<8192, blk, 0, stream>>>(y, x, 1, g1, be1, x1, 0);

    // ff = relu(x1 @ w1^T + b1)
    gemm_bt<<<dim3(32, 64), blk, 0, stream>>>(
        x1, w1T, b1, ff, 8192, 4096, 1024, 1024, 1024, 4096, 1);

    // y2 = ff @ w2^T + b2
    gemm_bt<<<dim3(8, 64), blk, 0, stream>>>(
        ff, w2T, b2, y2, 8192, 1024, 4096, 4096, 4096, 1024, 0);

    // out = LN(y2 + x1)
    add_ln<<<8192, blk, 0, stream>>>(y2, x1, 0, g2, be2, out, 1);
}